// Round 4
// baseline (1069.353 us; speedup 1.0000x reference)
//
#include <hip/hip_runtime.h>

#define N_NODES 100000
#define N_EDGES 3200000
#define N_GRAPHS 2048
#define MOL 78
#define HID 32
#define OUTD 128
#define BN_EPS 1e-5f

// Bucketed CSR build: 64 nodes per bucket
#define BNODES 64
#define NB ((N_NODES + BNODES - 1) / BNODES)  // 1563
#define BCAP 2560  // mean 2048, sigma ~45 -> 11 sigma headroom

// ---------------- CSR build (2-level bucket sort) ----------------

__global__ void binA_kernel(const int* __restrict__ src, const int* __restrict__ dst,
                            int* __restrict__ bcnt, int* __restrict__ bpack) {
    int e = blockIdx.x * blockDim.x + threadIdx.x;
    if (e >= N_EDGES) return;
    int d = dst[e];
    int b = d >> 6;
    int p = atomicAdd(&bcnt[b], 1);
    bpack[(size_t)b * BCAP + p] = (src[e] << 6) | (d & 63);
}

__global__ void bscan_kernel(const int* __restrict__ bcnt, int* __restrict__ bbase,
                             int* __restrict__ row_start) {
    // one block of 256; each thread handles 7 consecutive buckets (7*256=1792 >= NB)
    int t = threadIdx.x;
    int v[7];
    int tot = 0;
#pragma unroll
    for (int k = 0; k < 7; k++) {
        int i = t * 7 + k;
        v[k] = (i < NB) ? bcnt[i] : 0;
        tot += v[k];
    }
    __shared__ int sc[256];
    sc[t] = tot;
    __syncthreads();
    for (int off = 1; off < 256; off <<= 1) {
        int add = (t >= off) ? sc[t - off] : 0;
        __syncthreads();
        sc[t] += add;
        __syncthreads();
    }
    int run = sc[t] - tot;  // exclusive prefix
#pragma unroll
    for (int k = 0; k < 7; k++) {
        int i = t * 7 + k;
        if (i < NB) bbase[i] = run;
        run += v[k];
    }
    if (t == 0) row_start[N_NODES] = N_EDGES;
}

__global__ __launch_bounds__(256) void binB_kernel(const int* __restrict__ bcnt,
                                                   const int* __restrict__ bbase,
                                                   const int* __restrict__ bpack,
                                                   int* __restrict__ row_start,
                                                   int* __restrict__ csr) {
    int b = blockIdx.x;
    int t = threadIdx.x;
    __shared__ int ldeg[BNODES];
    __shared__ int lcur[BNODES];
    if (t < BNODES) ldeg[t] = 0;
    __syncthreads();
    int cnt = bcnt[b];
    int base = bbase[b];
    const int* bp = bpack + (size_t)b * BCAP;
    for (int i = t; i < cnt; i += 256) atomicAdd(&ldeg[bp[i] & 63], 1);
    __syncthreads();
    if (t < BNODES) {
        int v = ldeg[t];
        int p = v;
#pragma unroll
        for (int off = 1; off < BNODES; off <<= 1) {
            int u = __shfl_up(p, off, 64);
            if (t >= off) p += u;
        }
        int excl = p - v;
        lcur[t] = excl;
        int node = b * BNODES + t;
        if (node < N_NODES) row_start[node] = base + excl;
    }
    __syncthreads();
    for (int i = t; i < cnt; i += 256) {
        int pk = bp[i];
        int p = atomicAdd(&lcur[pk & 63], 1);
        csr[base + p] = pk >> 6;
    }
}

// ---------------- Projection (x/h -> y = [affine(x)] @ W1), f32 output ----------------

template <int KIN, bool AFFINE>
__global__ __launch_bounds__(256) void proj_kernel(const float* __restrict__ in,
                                                   const float* __restrict__ W1,
                                                   const float* __restrict__ scsh,
                                                   float* __restrict__ y) {
    __shared__ float w1s[KIN * HID];
    __shared__ float aff[2 * HID];
    for (int i = threadIdx.x; i < KIN * HID; i += 256) w1s[i] = W1[i];
    if (AFFINE && threadIdx.x < 2 * HID) aff[threadIdx.x] = scsh[threadIdx.x];
    __syncthreads();
    const int node = blockIdx.x * 256 + threadIdx.x;
    if (node >= N_NODES) return;
    const float* row = in + (size_t)node * KIN;
    float acc[HID];
#pragma unroll
    for (int j = 0; j < HID; j++) acc[j] = 0.f;
    const float4* w1v = (const float4*)w1s;
    for (int k = 0; k < KIN; k++) {
        float xv = row[k];
        if (AFFINE) xv = fmaf(xv, aff[k], aff[HID + k]);
#pragma unroll
        for (int q = 0; q < 8; q++) {
            float4 wv = w1v[k * 8 + q];
            acc[4 * q + 0] = fmaf(xv, wv.x, acc[4 * q + 0]);
            acc[4 * q + 1] = fmaf(xv, wv.y, acc[4 * q + 1]);
            acc[4 * q + 2] = fmaf(xv, wv.z, acc[4 * q + 2]);
            acc[4 * q + 3] = fmaf(xv, wv.w, acc[4 * q + 3]);
        }
    }
    float4* o = (float4*)(y + (size_t)node * HID);
#pragma unroll
    for (int q = 0; q < 8; q++)
        o[q] = make_float4(acc[4 * q], acc[4 * q + 1], acc[4 * q + 2], acc[4 * q + 3]);
}

// ---------------- Aggregation: pure 32-dim f32 sum over CSR ----------------
// Half-wave (32 lanes) per node: 4 edge slots x 8 lanes, each lane reads float4
// (8 lanes x 16B = one coalesced 128B row). Unroll x2 -> 8 rows in flight.

__global__ __launch_bounds__(256) void agg_kernel(const float* __restrict__ y,
                                                  const int* __restrict__ rs,
                                                  const int* __restrict__ csr,
                                                  float* __restrict__ agg) {
    int gt = blockIdx.x * blockDim.x + threadIdx.x;
    int node = gt >> 5;
    if (node >= N_NODES) return;
    int hl = threadIdx.x & 31;  // lane within half-wave
    int s = hl >> 3;            // edge slot 0..3
    int q = hl & 7;             // float4 quad (channels 4q..4q+3)
    const float4* rows = (const float4*)y;
    float4 acc = (s == 0) ? rows[(size_t)node * 8 + q] : make_float4(0.f, 0.f, 0.f, 0.f);
    int e0 = rs[node], e1 = rs[node + 1];
    int k = e0 + s;
    for (; k + 4 < e1; k += 8) {
        int j0 = csr[k];
        int j1 = csr[k + 4];
        float4 v0 = rows[(size_t)j0 * 8 + q];
        float4 v1 = rows[(size_t)j1 * 8 + q];
        acc.x += v0.x + v1.x;
        acc.y += v0.y + v1.y;
        acc.z += v0.z + v1.z;
        acc.w += v0.w + v1.w;
    }
    if (k < e1) {
        int j = csr[k];
        float4 v = rows[(size_t)j * 8 + q];
        acc.x += v.x;
        acc.y += v.y;
        acc.z += v.z;
        acc.w += v.w;
    }
#pragma unroll
    for (int m = 8; m <= 16; m <<= 1) {
        acc.x += __shfl_xor(acc.x, m, 32);
        acc.y += __shfl_xor(acc.y, m, 32);
        acc.z += __shfl_xor(acc.z, m, 32);
        acc.w += __shfl_xor(acc.w, m, 32);
    }
    if (s == 0) ((float4*)agg)[(size_t)node * 8 + q] = acc;
}

// ---------------- Second half of MLP + BN stats ----------------

__global__ __launch_bounds__(256) void mlp2_kernel(const float* __restrict__ agg,
                                                   const float* __restrict__ B1,
                                                   const float* __restrict__ W2,
                                                   const float* __restrict__ B2,
                                                   float* __restrict__ out,
                                                   float* __restrict__ sums) {
    __shared__ float w2s[HID * HID];
    __shared__ float bs[2 * HID];
    __shared__ float ssum[2 * HID];
    for (int i = threadIdx.x; i < HID * HID; i += 256) w2s[i] = W2[i];
    if (threadIdx.x < HID) {
        bs[threadIdx.x] = B1[threadIdx.x];
        bs[HID + threadIdx.x] = B2[threadIdx.x];
    }
    if (threadIdx.x < 2 * HID) ssum[threadIdx.x] = 0.f;
    __syncthreads();

    const int node = blockIdx.x * 256 + threadIdx.x;
    const bool active = node < N_NODES;

    float v[HID];
#pragma unroll
    for (int j = 0; j < HID; j++) v[j] = 0.f;
    if (active) {
        const float4* a = (const float4*)(agg + (size_t)node * HID);
#pragma unroll
        for (int q = 0; q < 8; q++) {
            float4 t = a[q];
            v[4 * q + 0] = t.x;
            v[4 * q + 1] = t.y;
            v[4 * q + 2] = t.z;
            v[4 * q + 3] = t.w;
        }
    }
#pragma unroll
    for (int j = 0; j < HID; j++) v[j] = fmaxf(v[j] + bs[j], 0.f);

    float h2[HID];
#pragma unroll
    for (int j = 0; j < HID; j++) h2[j] = bs[HID + j];
    const float4* w2v = (const float4*)w2s;
#pragma unroll
    for (int k = 0; k < HID; k++) {
        float z = v[k];
#pragma unroll
        for (int q = 0; q < 8; q++) {
            float4 wv = w2v[k * 8 + q];
            h2[4 * q + 0] = fmaf(z, wv.x, h2[4 * q + 0]);
            h2[4 * q + 1] = fmaf(z, wv.y, h2[4 * q + 1]);
            h2[4 * q + 2] = fmaf(z, wv.z, h2[4 * q + 2]);
            h2[4 * q + 3] = fmaf(z, wv.w, h2[4 * q + 3]);
        }
    }
#pragma unroll
    for (int j = 0; j < HID; j++) h2[j] = fmaxf(h2[j], 0.f);

    if (active) {
        float4* o = (float4*)(out + (size_t)node * HID);
#pragma unroll
        for (int q = 0; q < 8; q++)
            o[q] = make_float4(h2[4 * q], h2[4 * q + 1], h2[4 * q + 2], h2[4 * q + 3]);
    }

    int lane = threadIdx.x & 63;
#pragma unroll
    for (int j = 0; j < HID; j++) {
        float a = active ? h2[j] : 0.f;
        float a2 = a * a;
#pragma unroll
        for (int off = 32; off; off >>= 1) {
            a += __shfl_down(a, off, 64);
            a2 += __shfl_down(a2, off, 64);
        }
        if (lane == 0) {
            atomicAdd(&ssum[j], a);
            atomicAdd(&ssum[HID + j], a2);
        }
    }
    __syncthreads();
    if (threadIdx.x < 2 * HID) atomicAdd(&sums[threadIdx.x], ssum[threadIdx.x]);
}

__global__ void bnfin_kernel(const float* __restrict__ sums, const float* __restrict__ g,
                             const float* __restrict__ bt, float* __restrict__ scsh) {
    int j = threadIdx.x;
    if (j < HID) {
        float m = sums[j] * (1.0f / N_NODES);
        float var = sums[HID + j] * (1.0f / N_NODES) - m * m;
        var = fmaxf(var, 0.f);
        float sc = g[j] * rsqrtf(var + BN_EPS);
        scsh[j] = sc;
        scsh[HID + j] = bt[j] - m * sc;
    }
}

// ---------------- Pooling + FC ----------------

__global__ void pool_kernel(const float* __restrict__ h, const int* __restrict__ batch,
                            const float* __restrict__ scsh, float* __restrict__ pooled) {
    int gt = blockIdx.x * blockDim.x + threadIdx.x;
    if (gt >= N_NODES * HID) return;
    int node = gt >> 5;
    int c = gt & 31;
    int g = batch[node];
    float v = fmaf(h[gt], scsh[c], scsh[HID + c]);
    atomicAdd(&pooled[g * HID + c], v);
}

__global__ void fc_kernel(const float* __restrict__ pooled, const float* __restrict__ fcw,
                          const float* __restrict__ fcb, float* __restrict__ out) {
    __shared__ float w[HID * OUTD];
    for (int i = threadIdx.x; i < HID * OUTD; i += 256) w[i] = fcw[i];
    __syncthreads();
    int idx = blockIdx.x * 256 + threadIdx.x;
    if (idx >= N_GRAPHS * OUTD) return;
    int g = idx >> 7;
    int o = idx & 127;
    float acc = fcb[o];
#pragma unroll
    for (int k = 0; k < HID; k++) acc = fmaf(pooled[g * HID + k], w[k * OUTD + o], acc);
    out[idx] = fmaxf(acc, 0.f);
}

// ---------------- Launch ----------------

extern "C" void kernel_launch(void* const* d_in, const int* in_sizes, int n_in,
                              void* d_out, int out_size, void* d_ws, size_t ws_size,
                              hipStream_t stream) {
    const float* x = (const float*)d_in[0];
    const int* ei = (const int*)d_in[1];
    const int* batch = (const int*)d_in[2];
    const float* w1_0 = (const float*)d_in[3];
    const float* b1_0 = (const float*)d_in[4];
    const float* w2_0 = (const float*)d_in[5];
    const float* b2_0 = (const float*)d_in[6];
    const float* w1 = (const float*)d_in[7];
    const float* b1 = (const float*)d_in[8];
    const float* w2 = (const float*)d_in[9];
    const float* b2 = (const float*)d_in[10];
    const float* gamma = (const float*)d_in[11];
    const float* beta = (const float*)d_in[12];
    const float* fc_w = (const float*)d_in[13];
    const float* fc_b = (const float*)d_in[14];
    float* out = (float*)d_out;

    const int* e_src = ei;
    const int* e_dst = ei + N_EDGES;

    char* ws = (char*)d_ws;
    size_t off = 0;
    auto alloc = [&](size_t n) {
        void* p = ws + off;
        off += (n + 255) & ~(size_t)255;
        return p;
    };
    int* row_start = (int*)alloc((size_t)(N_NODES + 1) * 4);
    int* csr = (int*)alloc((size_t)N_EDGES * 4);
    int* bcnt = (int*)alloc((size_t)NB * 4);
    int* bbase = (int*)alloc((size_t)NB * 4);
    int* bpack = (int*)alloc((size_t)NB * BCAP * 4);
    float* ybuf = (float*)alloc((size_t)N_NODES * HID * 4);
    float* aggb = (float*)alloc((size_t)N_NODES * HID * 4);
    float* hbuf = (float*)alloc((size_t)N_NODES * HID * 4);
    float* bnsums = (float*)alloc(5 * 2 * HID * 4);
    float* scsh = (float*)alloc(5 * 2 * HID * 4);
    float* pooled = (float*)alloc((size_t)N_GRAPHS * HID * 4);

    hipMemsetAsync(bcnt, 0, (size_t)NB * 4, stream);
    hipMemsetAsync(bnsums, 0, 5 * 2 * HID * 4, stream);
    hipMemsetAsync(pooled, 0, (size_t)N_GRAPHS * HID * 4, stream);

    // CSR build: 2-level bucket sort
    binA_kernel<<<(N_EDGES + 255) / 256, 256, 0, stream>>>(e_src, e_dst, bcnt, bpack);
    bscan_kernel<<<1, 256, 0, stream>>>(bcnt, bbase, row_start);
    binB_kernel<<<NB, 256, 0, stream>>>(bcnt, bbase, bpack, row_start, csr);

    const int nodeBlocks = (N_NODES + 255) / 256;
    const int aggBlocks = (N_NODES * 32 + 255) / 256;

    // Layer 0: project 78->32 first (agg commutes with W1), then aggregate
    proj_kernel<MOL, false><<<nodeBlocks, 256, 0, stream>>>(x, w1_0, nullptr, ybuf);
    agg_kernel<<<aggBlocks, 256, 0, stream>>>(ybuf, row_start, csr, aggb);
    mlp2_kernel<<<nodeBlocks, 256, 0, stream>>>(aggb, b1_0, w2_0, b2_0, hbuf, bnsums);
    bnfin_kernel<<<1, 64, 0, stream>>>(bnsums, gamma, beta, scsh);

    // Layers 1..4: fold BN affine into projection, aggregate pure sums
    for (int l = 1; l < 5; l++) {
        int i = l - 1;
        proj_kernel<HID, true><<<nodeBlocks, 256, 0, stream>>>(
            hbuf, w1 + (size_t)i * HID * HID, scsh + (l - 1) * 2 * HID, ybuf);
        agg_kernel<<<aggBlocks, 256, 0, stream>>>(ybuf, row_start, csr, aggb);
        mlp2_kernel<<<nodeBlocks, 256, 0, stream>>>(
            aggb, b1 + (size_t)i * HID, w2 + (size_t)i * HID * HID, b2 + (size_t)i * HID,
            hbuf, bnsums + l * 2 * HID);
        bnfin_kernel<<<1, 64, 0, stream>>>(bnsums + l * 2 * HID, gamma + l * HID,
                                           beta + l * HID, scsh + l * 2 * HID);
    }

    // Pool + FC
    pool_kernel<<<(N_NODES * HID + 255) / 256, 256, 0, stream>>>(hbuf, batch, scsh + 4 * 2 * HID,
                                                                 pooled);
    fc_kernel<<<(N_GRAPHS * OUTD + 255) / 256, 256, 0, stream>>>(pooled, fc_w, fc_b, out);
}

// Round 5
// 633.132 us; speedup vs baseline: 1.6890x; 1.6890x over previous
//
#include <hip/hip_runtime.h>

#define N_NODES 100000
#define N_EDGES 3200000
#define N_GRAPHS 2048
#define MOL 78
#define HID 32
#define OUTD 128
#define BN_EPS 1e-5f

// Partition: buckets of 256 nodes (dst >> 8)
#define NBUCK ((N_NODES + 255) / 256)  // 391
#define BCAP2 9216                     // mean 8184, sigma ~90 -> +11 sigma
#define EPB 4096                       // edges per part1 block
#define P1_BLOCKS ((N_EDGES + EPB - 1) / EPB)  // 782

// ---------------- CSR build: LDS-staged two-pass bucket sort ----------------

__global__ __launch_bounds__(256) void part1_kernel(const int* __restrict__ src,
                                                    const int* __restrict__ dst,
                                                    int* __restrict__ gcur,
                                                    int* __restrict__ staging) {
    __shared__ int hist[NBUCK];
    __shared__ int lofs[NBUCK];
    __shared__ int lcur[NBUCK];
    __shared__ int gb[NBUCK];
    __shared__ int pk[EPB];
    __shared__ unsigned short bkt[EPB];
    __shared__ int sc[256];
    const int t = threadIdx.x;
    const int base = blockIdx.x * EPB;
    const int nedge = min(EPB, N_EDGES - base);

    for (int i = t; i < NBUCK; i += 256) hist[i] = 0;
    __syncthreads();
    for (int i = t; i < nedge; i += 256) atomicAdd(&hist[dst[base + i] >> 8], 1);
    __syncthreads();

    // exclusive scan of hist[0..NBUCK): each thread owns 2 consecutive slots
    int a0 = (2 * t < NBUCK) ? hist[2 * t] : 0;
    int a1 = (2 * t + 1 < NBUCK) ? hist[2 * t + 1] : 0;
    int tot = a0 + a1;
    sc[t] = tot;
    __syncthreads();
    for (int off = 1; off < 256; off <<= 1) {
        int add = (t >= off) ? sc[t - off] : 0;
        __syncthreads();
        sc[t] += add;
        __syncthreads();
    }
    int excl = sc[t] - tot;
    if (2 * t < NBUCK) { lofs[2 * t] = excl; lcur[2 * t] = excl; }
    if (2 * t + 1 < NBUCK) { lofs[2 * t + 1] = excl + a0; lcur[2 * t + 1] = excl + a0; }
    __syncthreads();

    // reorder into LDS by bucket
    for (int i = t; i < nedge; i += 256) {
        int d = dst[base + i];
        int s = src[base + i];
        int b = d >> 8;
        int p = atomicAdd(&lcur[b], 1);
        pk[p] = (s << 8) | (d & 255);
        bkt[p] = (unsigned short)b;
    }
    __syncthreads();

    // reserve global staging space: one atomic per (block, nonempty bucket)
    for (int b = t; b < NBUCK; b += 256) {
        int c = lcur[b] - lofs[b];
        gb[b] = c ? atomicAdd(&gcur[b], c) : 0;
    }
    __syncthreads();

    // copy runs out (consecutive i -> consecutive dest within a bucket run)
    for (int i = t; i < nedge; i += 256) {
        int b = bkt[i];
        staging[(size_t)b * BCAP2 + gb[b] + (i - lofs[b])] = pk[i];
    }
}

__global__ void csrbase_kernel(const int* __restrict__ gcur, int* __restrict__ bbase,
                               int* __restrict__ row_start) {
    int t = threadIdx.x;
    int a0 = (2 * t < NBUCK) ? gcur[2 * t] : 0;
    int a1 = (2 * t + 1 < NBUCK) ? gcur[2 * t + 1] : 0;
    int tot = a0 + a1;
    __shared__ int sc[256];
    sc[t] = tot;
    __syncthreads();
    for (int off = 1; off < 256; off <<= 1) {
        int add = (t >= off) ? sc[t - off] : 0;
        __syncthreads();
        sc[t] += add;
        __syncthreads();
    }
    int excl = sc[t] - tot;
    if (2 * t < NBUCK) bbase[2 * t] = excl;
    if (2 * t + 1 < NBUCK) bbase[2 * t + 1] = excl + a0;
    if (t == 0) row_start[N_NODES] = N_EDGES;
}

__global__ __launch_bounds__(256) void part2_kernel(const int* __restrict__ gcur,
                                                    const int* __restrict__ bbase,
                                                    const int* __restrict__ staging,
                                                    int* __restrict__ row_start,
                                                    int* __restrict__ csr) {
    int b = blockIdx.x, t = threadIdx.x;
    __shared__ int ldeg[256];
    __shared__ int lex[256];
    __shared__ int sc[256];
    ldeg[t] = 0;
    __syncthreads();
    int cnt = gcur[b];
    int base = bbase[b];
    const int* sp = staging + (size_t)b * BCAP2;
    for (int i = t; i < cnt; i += 256) atomicAdd(&ldeg[sp[i] & 255], 1);
    __syncthreads();
    int v = ldeg[t];
    sc[t] = v;
    __syncthreads();
    for (int off = 1; off < 256; off <<= 1) {
        int add = (t >= off) ? sc[t - off] : 0;
        __syncthreads();
        sc[t] += add;
        __syncthreads();
    }
    int excl = sc[t] - v;
    int node = b * 256 + t;
    if (node < N_NODES) row_start[node] = base + excl;
    lex[t] = base + excl;
    __syncthreads();
    for (int i = t; i < cnt; i += 256) {
        int pk = sp[i];
        int p = atomicAdd(&lex[pk & 255], 1);
        csr[p] = pk >> 8;
    }
}

// ---------------- Projection (x/h -> y = [affine(x)] @ W1), f32 output ----------------

template <int KIN, bool AFFINE>
__global__ __launch_bounds__(256) void proj_kernel(const float* __restrict__ in,
                                                   const float* __restrict__ W1,
                                                   const float* __restrict__ scsh,
                                                   float* __restrict__ y) {
    __shared__ float w1s[KIN * HID];
    __shared__ float aff[2 * HID];
    for (int i = threadIdx.x; i < KIN * HID; i += 256) w1s[i] = W1[i];
    if (AFFINE && threadIdx.x < 2 * HID) aff[threadIdx.x] = scsh[threadIdx.x];
    __syncthreads();
    const int node = blockIdx.x * 256 + threadIdx.x;
    if (node >= N_NODES) return;
    const float* row = in + (size_t)node * KIN;
    float acc[HID];
#pragma unroll
    for (int j = 0; j < HID; j++) acc[j] = 0.f;
    const float4* w1v = (const float4*)w1s;
    for (int k = 0; k < KIN; k++) {
        float xv = row[k];
        if (AFFINE) xv = fmaf(xv, aff[k], aff[HID + k]);
#pragma unroll
        for (int q = 0; q < 8; q++) {
            float4 wv = w1v[k * 8 + q];
            acc[4 * q + 0] = fmaf(xv, wv.x, acc[4 * q + 0]);
            acc[4 * q + 1] = fmaf(xv, wv.y, acc[4 * q + 1]);
            acc[4 * q + 2] = fmaf(xv, wv.z, acc[4 * q + 2]);
            acc[4 * q + 3] = fmaf(xv, wv.w, acc[4 * q + 3]);
        }
    }
    float4* o = (float4*)(y + (size_t)node * HID);
#pragma unroll
    for (int q = 0; q < 8; q++)
        o[q] = make_float4(acc[4 * q], acc[4 * q + 1], acc[4 * q + 2], acc[4 * q + 3]);
}

// ---------------- Aggregation: pure 32-dim f32 sum over CSR ----------------

__global__ __launch_bounds__(256) void agg_kernel(const float* __restrict__ y,
                                                  const int* __restrict__ rs,
                                                  const int* __restrict__ csr,
                                                  float* __restrict__ agg) {
    int gt = blockIdx.x * blockDim.x + threadIdx.x;
    int node = gt >> 5;
    if (node >= N_NODES) return;
    int hl = threadIdx.x & 31;  // lane within half-wave
    int s = hl >> 3;            // edge slot 0..3
    int q = hl & 7;             // float4 quad (channels 4q..4q+3)
    const float4* rows = (const float4*)y;
    float4 acc = (s == 0) ? rows[(size_t)node * 8 + q] : make_float4(0.f, 0.f, 0.f, 0.f);
    int e0 = rs[node], e1 = rs[node + 1];
    int k = e0 + s;
    for (; k + 4 < e1; k += 8) {
        int j0 = csr[k];
        int j1 = csr[k + 4];
        float4 v0 = rows[(size_t)j0 * 8 + q];
        float4 v1 = rows[(size_t)j1 * 8 + q];
        acc.x += v0.x + v1.x;
        acc.y += v0.y + v1.y;
        acc.z += v0.z + v1.z;
        acc.w += v0.w + v1.w;
    }
    if (k < e1) {
        int j = csr[k];
        float4 v = rows[(size_t)j * 8 + q];
        acc.x += v.x;
        acc.y += v.y;
        acc.z += v.z;
        acc.w += v.w;
    }
#pragma unroll
    for (int m = 8; m <= 16; m <<= 1) {
        acc.x += __shfl_xor(acc.x, m, 32);
        acc.y += __shfl_xor(acc.y, m, 32);
        acc.z += __shfl_xor(acc.z, m, 32);
        acc.w += __shfl_xor(acc.w, m, 32);
    }
    if (s == 0) ((float4*)agg)[(size_t)node * 8 + q] = acc;
}

// ---------------- Second half of MLP + BN stats ----------------

__global__ __launch_bounds__(256) void mlp2_kernel(const float* __restrict__ agg,
                                                   const float* __restrict__ B1,
                                                   const float* __restrict__ W2,
                                                   const float* __restrict__ B2,
                                                   float* __restrict__ out,
                                                   float* __restrict__ sums) {
    __shared__ float w2s[HID * HID];
    __shared__ float bs[2 * HID];
    __shared__ float ssum[2 * HID];
    for (int i = threadIdx.x; i < HID * HID; i += 256) w2s[i] = W2[i];
    if (threadIdx.x < HID) {
        bs[threadIdx.x] = B1[threadIdx.x];
        bs[HID + threadIdx.x] = B2[threadIdx.x];
    }
    if (threadIdx.x < 2 * HID) ssum[threadIdx.x] = 0.f;
    __syncthreads();

    const int node = blockIdx.x * 256 + threadIdx.x;
    const bool active = node < N_NODES;

    float v[HID];
#pragma unroll
    for (int j = 0; j < HID; j++) v[j] = 0.f;
    if (active) {
        const float4* a = (const float4*)(agg + (size_t)node * HID);
#pragma unroll
        for (int q = 0; q < 8; q++) {
            float4 t = a[q];
            v[4 * q + 0] = t.x;
            v[4 * q + 1] = t.y;
            v[4 * q + 2] = t.z;
            v[4 * q + 3] = t.w;
        }
    }
#pragma unroll
    for (int j = 0; j < HID; j++) v[j] = fmaxf(v[j] + bs[j], 0.f);

    float h2[HID];
#pragma unroll
    for (int j = 0; j < HID; j++) h2[j] = bs[HID + j];
    const float4* w2v = (const float4*)w2s;
#pragma unroll
    for (int k = 0; k < HID; k++) {
        float z = v[k];
#pragma unroll
        for (int q = 0; q < 8; q++) {
            float4 wv = w2v[k * 8 + q];
            h2[4 * q + 0] = fmaf(z, wv.x, h2[4 * q + 0]);
            h2[4 * q + 1] = fmaf(z, wv.y, h2[4 * q + 1]);
            h2[4 * q + 2] = fmaf(z, wv.z, h2[4 * q + 2]);
            h2[4 * q + 3] = fmaf(z, wv.w, h2[4 * q + 3]);
        }
    }
#pragma unroll
    for (int j = 0; j < HID; j++) h2[j] = fmaxf(h2[j], 0.f);

    if (active) {
        float4* o = (float4*)(out + (size_t)node * HID);
#pragma unroll
        for (int q = 0; q < 8; q++)
            o[q] = make_float4(h2[4 * q], h2[4 * q + 1], h2[4 * q + 2], h2[4 * q + 3]);
    }

    int lane = threadIdx.x & 63;
#pragma unroll
    for (int j = 0; j < HID; j++) {
        float a = active ? h2[j] : 0.f;
        float a2 = a * a;
#pragma unroll
        for (int off = 32; off; off >>= 1) {
            a += __shfl_down(a, off, 64);
            a2 += __shfl_down(a2, off, 64);
        }
        if (lane == 0) {
            atomicAdd(&ssum[j], a);
            atomicAdd(&ssum[HID + j], a2);
        }
    }
    __syncthreads();
    if (threadIdx.x < 2 * HID) atomicAdd(&sums[threadIdx.x], ssum[threadIdx.x]);
}

__global__ void bnfin_kernel(const float* __restrict__ sums, const float* __restrict__ g,
                             const float* __restrict__ bt, float* __restrict__ scsh) {
    int j = threadIdx.x;
    if (j < HID) {
        float m = sums[j] * (1.0f / N_NODES);
        float var = sums[HID + j] * (1.0f / N_NODES) - m * m;
        var = fmaxf(var, 0.f);
        float sc = g[j] * rsqrtf(var + BN_EPS);
        scsh[j] = sc;
        scsh[HID + j] = bt[j] - m * sc;
    }
}

// ---------------- Pooling + FC ----------------

__global__ void pool_kernel(const float* __restrict__ h, const int* __restrict__ batch,
                            const float* __restrict__ scsh, float* __restrict__ pooled) {
    int gt = blockIdx.x * blockDim.x + threadIdx.x;
    if (gt >= N_NODES * HID) return;
    int node = gt >> 5;
    int c = gt & 31;
    int g = batch[node];
    float v = fmaf(h[gt], scsh[c], scsh[HID + c]);
    atomicAdd(&pooled[g * HID + c], v);
}

__global__ void fc_kernel(const float* __restrict__ pooled, const float* __restrict__ fcw,
                          const float* __restrict__ fcb, float* __restrict__ out) {
    __shared__ float w[HID * OUTD];
    for (int i = threadIdx.x; i < HID * OUTD; i += 256) w[i] = fcw[i];
    __syncthreads();
    int idx = blockIdx.x * 256 + threadIdx.x;
    if (idx >= N_GRAPHS * OUTD) return;
    int g = idx >> 7;
    int o = idx & 127;
    float acc = fcb[o];
#pragma unroll
    for (int k = 0; k < HID; k++) acc = fmaf(pooled[g * HID + k], w[k * OUTD + o], acc);
    out[idx] = fmaxf(acc, 0.f);
}

// ---------------- Launch ----------------

extern "C" void kernel_launch(void* const* d_in, const int* in_sizes, int n_in,
                              void* d_out, int out_size, void* d_ws, size_t ws_size,
                              hipStream_t stream) {
    const float* x = (const float*)d_in[0];
    const int* ei = (const int*)d_in[1];
    const int* batch = (const int*)d_in[2];
    const float* w1_0 = (const float*)d_in[3];
    const float* b1_0 = (const float*)d_in[4];
    const float* w2_0 = (const float*)d_in[5];
    const float* b2_0 = (const float*)d_in[6];
    const float* w1 = (const float*)d_in[7];
    const float* b1 = (const float*)d_in[8];
    const float* w2 = (const float*)d_in[9];
    const float* b2 = (const float*)d_in[10];
    const float* gamma = (const float*)d_in[11];
    const float* beta = (const float*)d_in[12];
    const float* fc_w = (const float*)d_in[13];
    const float* fc_b = (const float*)d_in[14];
    float* out = (float*)d_out;

    const int* e_src = ei;
    const int* e_dst = ei + N_EDGES;

    char* ws = (char*)d_ws;
    size_t off = 0;
    auto alloc = [&](size_t n) {
        void* p = ws + off;
        off += (n + 255) & ~(size_t)255;
        return p;
    };
    int* row_start = (int*)alloc((size_t)(N_NODES + 1) * 4);
    int* csr = (int*)alloc((size_t)N_EDGES * 4);
    int* gcur = (int*)alloc((size_t)NBUCK * 4);
    int* bbase = (int*)alloc((size_t)NBUCK * 4);
    int* staging = (int*)alloc((size_t)NBUCK * BCAP2 * 4);
    float* ybuf = (float*)alloc((size_t)N_NODES * HID * 4);
    float* aggb = (float*)alloc((size_t)N_NODES * HID * 4);
    float* hbuf = (float*)alloc((size_t)N_NODES * HID * 4);
    float* bnsums = (float*)alloc(5 * 2 * HID * 4);
    float* scsh = (float*)alloc(5 * 2 * HID * 4);
    float* pooled = (float*)alloc((size_t)N_GRAPHS * HID * 4);

    hipMemsetAsync(gcur, 0, (size_t)NBUCK * 4, stream);
    hipMemsetAsync(bnsums, 0, 5 * 2 * HID * 4, stream);
    hipMemsetAsync(pooled, 0, (size_t)N_GRAPHS * HID * 4, stream);

    // CSR build: LDS-staged partition then per-bucket counting sort
    part1_kernel<<<P1_BLOCKS, 256, 0, stream>>>(e_src, e_dst, gcur, staging);
    csrbase_kernel<<<1, 256, 0, stream>>>(gcur, bbase, row_start);
    part2_kernel<<<NBUCK, 256, 0, stream>>>(gcur, bbase, staging, row_start, csr);

    const int nodeBlocks = (N_NODES + 255) / 256;
    const int aggBlocks = (N_NODES * 32 + 255) / 256;

    // Layer 0: project 78->32 first (agg commutes with W1), then aggregate
    proj_kernel<MOL, false><<<nodeBlocks, 256, 0, stream>>>(x, w1_0, nullptr, ybuf);
    agg_kernel<<<aggBlocks, 256, 0, stream>>>(ybuf, row_start, csr, aggb);
    mlp2_kernel<<<nodeBlocks, 256, 0, stream>>>(aggb, b1_0, w2_0, b2_0, hbuf, bnsums);
    bnfin_kernel<<<1, 64, 0, stream>>>(bnsums, gamma, beta, scsh);

    // Layers 1..4: fold BN affine into projection, aggregate pure sums
    for (int l = 1; l < 5; l++) {
        int i = l - 1;
        proj_kernel<HID, true><<<nodeBlocks, 256, 0, stream>>>(
            hbuf, w1 + (size_t)i * HID * HID, scsh + (l - 1) * 2 * HID, ybuf);
        agg_kernel<<<aggBlocks, 256, 0, stream>>>(ybuf, row_start, csr, aggb);
        mlp2_kernel<<<nodeBlocks, 256, 0, stream>>>(
            aggb, b1 + (size_t)i * HID, w2 + (size_t)i * HID * HID, b2 + (size_t)i * HID,
            hbuf, bnsums + l * 2 * HID);
        bnfin_kernel<<<1, 64, 0, stream>>>(bnsums + l * 2 * HID, gamma + l * HID,
                                           beta + l * HID, scsh + l * 2 * HID);
    }

    // Pool + FC
    pool_kernel<<<(N_NODES * HID + 255) / 256, 256, 0, stream>>>(hbuf, batch, scsh + 4 * 2 * HID,
                                                                 pooled);
    fc_kernel<<<(N_GRAPHS * OUTD + 255) / 256, 256, 0, stream>>>(pooled, fc_w, fc_b, out);
}